// Round 7
// baseline (733.975 us; speedup 1.0000x reference)
//
#include <hip/hip_runtime.h>
#include <hip/hip_cooperative_groups.h>

namespace cg = cooperative_groups;

// Grid2SeqTransformerBackbone on MI355X (gfx950) — single cooperative kernel
// (512 blocks = 2/CU, each block does 2 units/phase) with checked launch and
// a fallback to the verified 8-kernel pipeline if cooperative launch fails.
// R6 post-mortem: 1024-block coop launch was rejected (occupancy model caps
// LDS at 64KB/CU -> 3 blocks/CU max) and the error was unchecked -> zero output.

#define BB 16
#define SS 1024
#define NT (BB*SS)

typedef short bf8 __attribute__((ext_vector_type(8)));
typedef float f4 __attribute__((ext_vector_type(4)));
typedef unsigned short u16;
typedef unsigned short us4 __attribute__((ext_vector_type(4)));

#define MFMA(a,b,c) __builtin_amdgcn_mfma_f32_16x16x32_bf16(a,b,c,0,0,0)

__device__ __forceinline__ float b2f(u16 u){
  union { unsigned int i; float f; } v; v.i = ((unsigned int)u) << 16; return v.f;
}
__device__ __forceinline__ u16 f2b(float f){
  union { float f; unsigned int i; } v; v.f = f;
  unsigned int x = v.i;
  return (u16)((x + 0x7FFFu + ((x >> 16) & 1u)) >> 16);   // RNE
}
__device__ __forceinline__ int probe_f32(const void* ln1w){
  return ((const u16*)ln1w)[0] == 0;   // fp32 1.0f low half = 0x0000; bf16 = 0x3F80
}
__device__ __forceinline__ float ldf(const void* p, int i, int isf32){
  return isf32 ? ((const float*)p)[i] : b2f(((const u16*)p)[i]);
}
// tanh-GELU: g = x - x/(exp(2y)+1); |err| <~ 2e-3.
__device__ __forceinline__ float gelu(float x){
  float y = 1.5957691216f * x * (1.f + 0.044715f * x * x);
  float e = __expf(y);
  return x - x * __builtin_amdgcn_rcpf(e + 1.f);
}

// ---- converted-weight area offsets (u16 units, 16B-aligned) ----
#define O_EB   0
#define O_L1W  64
#define O_L1B  256
#define O_IPW  448
#define O_IPB  37312
#define O_OW   37888
#define O_OWB  50176
#define O_L2W  50368
#define O_L2B  50560
#define O_F1B  50752
#define O_F2B  51520

__device__ __forceinline__ void cv(u16* dst, const void* src, int n, int isf32,
                                   int tid, int nth){
  if (isf32){
    const float* s = (const float*)src;
    for (int i = tid; i < n; i += nth) dst[i] = f2b(s[i]);
  } else {
    const u16* s = (const u16*)src;
    for (int i = tid; i < n; i += nth) dst[i] = s[i];
  }
}

// QKV projection for j-tile jt (j = jt*16+col), A-frags a0/a1 (K=64).
// q,k stored [b][h][s][16]; v stored transposed [b][h][16][s].
__device__ __forceinline__ void qkv_jt(bf8 a0, bf8 a1, int jt, int lane,
    const u16* __restrict__ ipw, const u16* __restrict__ ipb,
    int bb4, int sw, u16* __restrict__ qb, u16* __restrict__ kb, u16* __restrict__ vt)
{
  int col = lane & 15, quad = lane >> 4;
  f4 acc = {0.f,0.f,0.f,0.f};
  bf8 b0 = *(const bf8*)(ipw + (jt*16+col)*64 + quad*8);
  bf8 b1 = *(const bf8*)(ipw + (jt*16+col)*64 + 32 + quad*8);
  acc = MFMA(a0, b0, acc);
  acc = MFMA(a1, b1, acc);
  int j = jt*16 + col;
  float bj = b2f(ipb[j]);
  if (j < 128){
    u16* dst = (j < 64) ? qb : kb;
    int jj = j & 63; int hd = jj >> 4, d = jj & 15;
    int base = (bb4 + hd)*1024 + sw + quad*4;
    #pragma unroll
    for (int r = 0; r < 4; r++) dst[((base + r) << 4) + d] = f2b(acc[r] + bj);
  } else {
    int jj = j - 128; int hd = jj >> 4, d = jj & 15;
    us4 pk;
    #pragma unroll
    for (int r = 0; r < 4; r++) pk[r] = f2b(acc[r] + bj);
    *(us4*)(vt + ((bb4 + hd)*16 + d)*1024 + sw + quad*4) = pk;
  }
}

// 4-way cross-wave LayerNorm: val = this wave's f-tile (f = wave) C-frag rows.
// Caller must __syncthreads() after return before reading other waves' columns.
__device__ __forceinline__ void ln4(f4 val, int wave, int col, int quad,
    const u16* __restrict__ w, const u16* __restrict__ bs,
    u16* als, float (*lnred)[16][2])
{
  float sm[4], sq[4];
  #pragma unroll
  for (int r = 0; r < 4; r++){ sm[r] = val[r]; sq[r] = val[r]*val[r]; }
  #pragma unroll
  for (int off = 1; off < 16; off <<= 1){
    #pragma unroll
    for (int r = 0; r < 4; r++){
      sm[r] += __shfl_xor(sm[r], off, 64);
      sq[r] += __shfl_xor(sq[r], off, 64);
    }
  }
  if (col == 0){
    #pragma unroll
    for (int r = 0; r < 4; r++){
      lnred[wave][quad*4 + r][0] = sm[r];
      lnred[wave][quad*4 + r][1] = sq[r];
    }
  }
  __syncthreads();
  int n = wave*16 + col;
  float ww = b2f(w[n]), bb = b2f(bs[n]);
  #pragma unroll
  for (int r = 0; r < 4; r++){
    int row = quad*4 + r;
    float s0 = lnred[0][row][0] + lnred[1][row][0] + lnred[2][row][0] + lnred[3][row][0];
    float q0 = lnred[0][row][1] + lnred[1][row][1] + lnred[2][row][1] + lnred[3][row][1];
    float m = s0 * 0.015625f;
    float rs = rsqrtf(fmaxf(q0*0.015625f - m*m, 0.f) + 1e-5f);
    als[row*72 + n] = f2b((val[r] - m)*rs*ww + bb);
  }
}

// ====================== cooperative single kernel ==========================
__global__ __launch_bounds__(256, 2) void k_all(
    const void* __restrict__ x,   const void* __restrict__ ew,
    const void* __restrict__ ebS, const void* __restrict__ l1wS,
    const void* __restrict__ l1bS,const void* __restrict__ ipwS,
    const void* __restrict__ ipbS,const void* __restrict__ owS,
    const void* __restrict__ owbS,const void* __restrict__ l2wS,
    const void* __restrict__ l2bS,const void* __restrict__ f1wS,
    const void* __restrict__ f1bS,const void* __restrict__ f2wS,
    const void* __restrict__ f2bS,
    u16* __restrict__ cb, u16* __restrict__ ewt,
    u16* __restrict__ f1t, u16* __restrict__ f2t,
    float* __restrict__ h, float* __restrict__ keepf,
    u16* __restrict__ qb, u16* __restrict__ kb, u16* __restrict__ vt,
    u16* __restrict__ obuf, void* __restrict__ outp)
{
  cg::grid_group grid = cg::this_grid();
  __shared__ __align__(16) u16 als[16*72];
  __shared__ __align__(16) u16 gls[16*264];
  __shared__ __align__(16) u16 xs[16*104];
  __shared__ __align__(16) u16 plds[4][16*40];
  __shared__ float lnred[4][16][2];            // total ~19.7 KB

  int tid  = threadIdx.x;
  int lane = tid & 63, wave = tid >> 6;
  int col  = lane & 15, quad = lane >> 4;
  int isf32 = probe_f32(l1wS);

  // phase 0: weight canonicalize + transposes
  {
    int gtid = blockIdx.x*256 + tid;
    int nth  = gridDim.x*256;
    for (int i = gtid; i < 64*96; i += nth){
      int n = i / 96, c = i % 96;
      ewt[i] = (c < 66) ? f2b(ldf(ew, c*64 + n, isf32)) : (u16)0;
    }
    for (int i = gtid; i < 3*256*64; i += nth){
      int l = i / (256*64); int r = i % (256*64); int n = r / 64, k = r % 64;
      f1t[i] = f2b(ldf(f1wS, (l*64 + k)*256 + n, isf32));
    }
    for (int i = gtid; i < 3*64*256; i += nth){
      int l = i / (64*256); int r = i % (64*256); int n = r / 256, k = r % 256;
      f2t[i] = f2b(ldf(f2wS, (l*256 + k)*64 + n, isf32));
    }
    cv(cb + O_EB,  ebS,  64,    isf32, gtid, nth);
    cv(cb + O_L1W, l1wS, 192,   isf32, gtid, nth);
    cv(cb + O_L1B, l1bS, 192,   isf32, gtid, nth);
    cv(cb + O_IPW, ipwS, 36864, isf32, gtid, nth);
    cv(cb + O_IPB, ipbS, 576,   isf32, gtid, nth);
    cv(cb + O_OW,  owS,  12288, isf32, gtid, nth);
    cv(cb + O_OWB, owbS, 192,   isf32, gtid, nth);
    cv(cb + O_L2W, l2wS, 192,   isf32, gtid, nth);
    cv(cb + O_L2B, l2bS, 192,   isf32, gtid, nth);
    cv(cb + O_F1B, f1bS, 768,   isf32, gtid, nth);
    cv(cb + O_F2B, f2bS, 192,   isf32, gtid, nth);
  }
  grid.sync();

  // phase 1: features + embed + LN1 + QKV(l=0); 2 units of 16 tokens per block
  for (int u = 0; u < 2; u++){
    int tw = (blockIdx.x + 512*u) * 16;
    int b = tw >> 10, sw = tw & 1023;
    for (int i = tid; i < 16*104; i += 256){
      int t = i / 104, c = i - t*104;
      int s = sw + t;
      float v;
      if (c < 64)       v = ldf(x, ((b << 6) + c)*1024 + s, isf32);
      else if (c == 64) v = -1.f + (2.f/31.f)*(float)(s & 31);
      else if (c == 65) v = -1.f + (2.f/31.f)*(float)((s >> 5) & 31);
      else              v = 0.f;
      xs[i] = f2b(v);
    }
    if (tid < 16){
      int s = sw + tid;
      float x6  = ldf(x, ((b << 6) + 6)*1024 + s, isf32);
      float x58 = ldf(x, ((b << 6) + 58)*1024 + s, isf32);
      keepf[(b << 10) + s] = (x6 != 0.f && x58 != 0.f) ? 0.f : 1.f;
    }
    __syncthreads();
    bf8 af0 = *(const bf8*)(xs + col*104 + quad*8);
    bf8 af1 = *(const bf8*)(xs + col*104 + 32 + quad*8);
    bf8 af2 = *(const bf8*)(xs + col*104 + 64 + quad*8);
    int f = wave;
    f4 acc = {0.f,0.f,0.f,0.f};
    acc = MFMA(af0, *(const bf8*)(ewt + (f*16+col)*96 + quad*8), acc);
    acc = MFMA(af1, *(const bf8*)(ewt + (f*16+col)*96 + 32 + quad*8), acc);
    acc = MFMA(af2, *(const bf8*)(ewt + (f*16+col)*96 + 64 + quad*8), acc);
    float bias = b2f(cb[O_EB + f*16 + col]);
    #pragma unroll
    for (int r = 0; r < 4; r++){
      acc[r] += bias;
      h[(tw + quad*4 + r)*64 + f*16 + col] = acc[r];
    }
    ln4(acc, wave, col, quad, cb + O_L1W, cb + O_L1B, als, lnred);
    __syncthreads();
    bf8 a0 = *(const bf8*)(als + col*72 + quad*8);
    bf8 a1 = *(const bf8*)(als + col*72 + 32 + quad*8);
    #pragma unroll
    for (int j = 0; j < 3; j++)
      qkv_jt(a0, a1, wave*3 + j, lane, cb + O_IPW, cb + O_IPB,
             b << 2, sw, qb, kb, vt);
    __syncthreads();   // protect xs/als before next unit overwrites
  }
  grid.sync();

  for (int l = 0; l < 3; l++){
    int nl = (l < 2) ? (l + 1) : 0;
    // attention: 2 units per block; both units share (b,h) (512 = 8*64)
    for (int u = 0; u < 2; u++){
      int blk = blockIdx.x + 512*u;
      int bh = blk & 63, qt = blk >> 6;
      int b = bh >> 2, hd = bh & 3;
      int q0 = qt*64 + wave*16;
      const u16* qbase = qb + (bh << 14);
      const u16* kbase = kb + (bh << 14);
      const u16* vbase = vt + (bh << 14);
      const float* kp = keepf + (b << 10);
      bf8 qf = {0,0,0,0,0,0,0,0};
      if (quad < 2) qf = *(const bf8*)(qbase + ((q0 + col) << 4) + quad*8);
      f4 oacc = {0.f,0.f,0.f,0.f};
      float l4v[4] = {0.f,0.f,0.f,0.f};
      u16* pw = plds[wave];
      for (int kc = 0; kc < 1024; kc += 32){
        #pragma unroll
        for (int t = 0; t < 2; t++){
          bf8 kf = {0,0,0,0,0,0,0,0};
          int key = kc + t*16 + col;
          if (quad < 2) kf = *(const bf8*)(kbase + (key << 4) + quad*8);
          f4 sc = {0.f,0.f,0.f,0.f};
          sc = MFMA(qf, kf, sc);
          float kpv = kp[key];
          #pragma unroll
          for (int r = 0; r < 4; r++){
            float p = kpv * __expf(fminf(sc[r] * 0.25f, 60.f));
            l4v[r] += p;
            pw[(quad*4 + r)*40 + t*16 + col] = f2b(p);
          }
        }
        bf8 pf = *(const bf8*)(pw + col*40 + quad*8);
        bf8 vf = *(const bf8*)(vbase + col*1024 + kc + quad*8);
        oacc = MFMA(pf, vf, oacc);
      }
      #pragma unroll
      for (int off = 1; off < 16; off <<= 1)
        #pragma unroll
        for (int r = 0; r < 4; r++) l4v[r] += __shfl_xor(l4v[r], off, 64);
      #pragma unroll
      for (int r = 0; r < 4; r++){
        int q = q0 + quad*4 + r;
        float rd = __builtin_amdgcn_rcpf(fmaxf(l4v[r], 1e-30f));
        obuf[((b << 10) + q)*64 + hd*16 + col] = f2b(oacc[r] * rd);
      }
    }
    grid.sync();
    // ff: 2 units of 16 tokens per block, 4-way N split
    {
      const u16* ow     = cb + O_OW  + l*4096;
      const u16* obias  = cb + O_OWB + l*64;
      const u16* f1b    = cb + O_F1B + l*256;
      const u16* f2bias = cb + O_F2B + l*64;
      const u16* f1l    = f1t + l*16384;
      const u16* f2l    = f2t + l*16384;
      for (int u = 0; u < 2; u++){
        int tw = (blockIdx.x + 512*u) * 16;
        int f = wave;
        bf8 af0 = *(const bf8*)(obuf + (tw + col)*64 + quad*8);
        bf8 af1 = *(const bf8*)(obuf + (tw + col)*64 + 32 + quad*8);
        f4 acc = {0.f,0.f,0.f,0.f};
        acc = MFMA(af0, *(const bf8*)(ow + (f*16+col)*64 + quad*8), acc);
        acc = MFMA(af1, *(const bf8*)(ow + (f*16+col)*64 + 32 + quad*8), acc);
        float bo = b2f(obias[f*16 + col]);
        f4 hfA;
        #pragma unroll
        for (int r = 0; r < 4; r++)
          hfA[r] = h[(tw + quad*4 + r)*64 + f*16 + col] + acc[r] + bo;
        ln4(hfA, wave, col, quad, cb + O_L2W + l*64, cb + O_L2B + l*64, als, lnred);
        __syncthreads();
        bf8 a0 = *(const bf8*)(als + col*72 + quad*8);
        bf8 a1 = *(const bf8*)(als + col*72 + 32 + quad*8);
        #pragma unroll
        for (int j = 0; j < 4; j++){
          int ft = wave*4 + j;
          f4 fa = {0.f,0.f,0.f,0.f};
          fa = MFMA(a0, *(const bf8*)(f1l + (ft*16+col)*64 + quad*8), fa);
          fa = MFMA(a1, *(const bf8*)(f1l + (ft*16+col)*64 + 32 + quad*8), fa);
          int n = ft*16 + col;
          float bb = b2f(f1b[n]);
          #pragma unroll
          for (int r = 0; r < 4; r++)
            gls[(quad*4 + r)*264 + n] = f2b(gelu(fa[r] + bb));
        }
        __syncthreads();
        bf8 gfr[8];
        #pragma unroll
        for (int kc = 0; kc < 8; kc++)
          gfr[kc] = *(const bf8*)(gls + col*264 + kc*32 + quad*8);
        f4 acc2 = {0.f,0.f,0.f,0.f};
        #pragma unroll
        for (int kc = 0; kc < 8; kc++)
          acc2 = MFMA(gfr[kc], *(const bf8*)(f2l + (f*16+col)*256 + kc*32 + quad*8), acc2);
        float b2v = b2f(f2bias[f*16 + col]);
        f4 hv;
        #pragma unroll
        for (int r = 0; r < 4; r++){
          float v = hfA[r] + acc2[r] + b2v;
          hv[r] = v;
          h[(tw + quad*4 + r)*64 + f*16 + col] = v;
        }
        if (l == 2){
          int bb = tw >> 10, sbase = (tw & 1023) + quad*4;
          float kpr[4];
          #pragma unroll
          for (int r = 0; r < 4; r++) kpr[r] = keepf[tw + quad*4 + r];
          #pragma unroll
          for (int r = 0; r < 4; r++){
            float v = hv[r] * kpr[r];
            long idx = (long)((bb << 6) + f*16 + col)*1024 + sbase + r;
            if (isf32) ((float*)outp)[idx] = v;
            else       ((u16*)outp)[idx]   = f2b(v);
          }
          __syncthreads();
        } else {
          ln4(hv, wave, col, quad, cb + O_L1W + nl*64, cb + O_L1B + nl*64, als, lnred);
          __syncthreads();
          bf8 qa0 = *(const bf8*)(als + col*72 + quad*8);
          bf8 qa1 = *(const bf8*)(als + col*72 + 32 + quad*8);
          int bb4 = (tw >> 10) << 2, sw = tw & 1023;
          #pragma unroll
          for (int j = 0; j < 3; j++)
            qkv_jt(qa0, qa1, wave*3 + j, lane, cb + O_IPW + nl*12288,
                   cb + O_IPB + nl*192, bb4, sw, qb, kb, vt);
          __syncthreads();
        }
      }
    }
    if (l < 2) grid.sync();
  }
}

// ====================== fallback: verified R5 pipeline =====================
__global__ __launch_bounds__(256) void k_conv(
    const void* ew, const void* eb, const void* l1w, const void* l1b,
    const void* ipw, const void* ipb, const void* ow, const void* owb,
    const void* l2w, const void* l2b, const void* f1w, const void* f1bp,
    const void* f2w, const void* f2bp, u16* __restrict__ cb,
    u16* __restrict__ ewt, u16* __restrict__ f1t, u16* __restrict__ f2t)
{
  int tid = blockIdx.x*256 + threadIdx.x;
  int nth = gridDim.x*256;
  int isf32 = probe_f32(l1w);
  for (int i = tid; i < 64*96; i += nth){
    int n = i / 96, c = i % 96;
    ewt[i] = (c < 66) ? f2b(ldf(ew, c*64 + n, isf32)) : (u16)0;
  }
  for (int i = tid; i < 3*256*64; i += nth){
    int l = i / (256*64); int r = i % (256*64); int n = r / 64, k = r % 64;
    f1t[i] = f2b(ldf(f1w, (l*64 + k)*256 + n, isf32));
  }
  for (int i = tid; i < 3*64*256; i += nth){
    int l = i / (64*256); int r = i % (64*256); int n = r / 256, k = r % 256;
    f2t[i] = f2b(ldf(f2w, (l*256 + k)*64 + n, isf32));
  }
  cv(cb + O_EB,  eb,   64,    isf32, tid, nth);
  cv(cb + O_L1W, l1w,  192,   isf32, tid, nth);
  cv(cb + O_L1B, l1b,  192,   isf32, tid, nth);
  cv(cb + O_IPW, ipw,  36864, isf32, tid, nth);
  cv(cb + O_IPB, ipb,  576,   isf32, tid, nth);
  cv(cb + O_OW,  ow,   12288, isf32, tid, nth);
  cv(cb + O_OWB, owb,  192,   isf32, tid, nth);
  cv(cb + O_L2W, l2w,  192,   isf32, tid, nth);
  cv(cb + O_L2B, l2b,  192,   isf32, tid, nth);
  cv(cb + O_F1B, f1bp, 768,   isf32, tid, nth);
  cv(cb + O_F2B, f2bp, 192,   isf32, tid, nth);
}

__device__ __forceinline__ void ln_to_lds(const f4* hf, int lane,
    const u16* __restrict__ w, const u16* __restrict__ bs, u16* als)
{
  int col = lane & 15, quad = lane >> 4;
  float sm[4], sq[4];
  #pragma unroll
  for (int r = 0; r < 4; r++){
    float a = 0.f, q2 = 0.f;
    #pragma unroll
    for (int f = 0; f < 4; f++){ float v = hf[f][r]; a += v; q2 += v*v; }
    sm[r] = a; sq[r] = q2;
  }
  #pragma unroll
  for (int off = 1; off < 16; off <<= 1){
    #pragma unroll
    for (int r = 0; r < 4; r++){
      sm[r] += __shfl_xor(sm[r], off, 64);
      sq[r] += __shfl_xor(sq[r], off, 64);
    }
  }
  #pragma unroll
  for (int r = 0; r < 4; r++){
    float m = sm[r] * 0.015625f;
    float rstd = rsqrtf(fmaxf(sq[r]*0.015625f - m*m, 0.f) + 1e-5f);
    sm[r] = m; sq[r] = rstd;
  }
  #pragma unroll
  for (int f = 0; f < 4; f++){
    int n = f*16 + col;
    float ww = b2f(w[n]), bb = b2f(bs[n]);
    #pragma unroll
    for (int r = 0; r < 4; r++)
      als[(quad*4 + r)*72 + n] = f2b((hf[f][r] - sm[r])*sq[r]*ww + bb);
  }
}

__global__ __launch_bounds__(256) void k0(const void* __restrict__ x,
    const void* __restrict__ dtype_probe,
    const u16* __restrict__ cb, const u16* __restrict__ ewt,
    float* __restrict__ h, float* __restrict__ keepf,
    u16* __restrict__ qb, u16* __restrict__ kb, u16* __restrict__ vt)
{
  __shared__ __align__(16) u16 xs[4][16*104];
  __shared__ __align__(16) u16 als[4][16*72];
  int lane = threadIdx.x & 63, wave = threadIdx.x >> 6;
  int col = lane & 15, quad = lane >> 4;
  int t0 = blockIdx.x*64;
  int b = t0 >> 10;
  int tw = t0 + wave*16;
  int sw = (t0 & 1023) + wave*16;
  u16* axs = xs[wave];
  int s = sw + col;
  int xf32 = probe_f32(dtype_probe);
  #pragma unroll
  for (int i = 0; i < 16; i++){
    int c = quad*16 + i;
    axs[col*104 + c] = f2b(ldf(x, ((b << 6) + c)*1024 + s, xf32));
  }
  #pragma unroll
  for (int i = 0; i < 8; i++){
    int c = 64 + quad*8 + i;
    float v = 0.f;
    if (c == 64)      v = -1.f + (2.f/31.f)*(float)(s & 31);
    else if (c == 65) v = -1.f + (2.f/31.f)*(float)((s >> 5) & 31);
    axs[col*104 + c] = f2b(v);
  }
  if (quad == 0){
    float x6  = ldf(x, ((b << 6) + 6)*1024 + s, xf32);
    float x58 = ldf(x, ((b << 6) + 58)*1024 + s, xf32);
    keepf[(b << 10) + s] = (x6 != 0.f && x58 != 0.f) ? 0.f : 1.f;
  }
  bf8 af[3];
  #pragma unroll
  for (int kc = 0; kc < 3; kc++) af[kc] = *(const bf8*)(axs + col*104 + kc*32 + quad*8);
  f4 hf[4];
  #pragma unroll
  for (int f = 0; f < 4; f++){
    f4 acc = {0.f,0.f,0.f,0.f};
    #pragma unroll
    for (int kc = 0; kc < 3; kc++){
      bf8 bfr = *(const bf8*)(ewt + (f*16+col)*96 + kc*32 + quad*8);
      acc = MFMA(af[kc], bfr, acc);
    }
    float bias = b2f(cb[O_EB + f*16 + col]);
    #pragma unroll
    for (int r = 0; r < 4; r++){
      acc[r] += bias;
      h[(tw + quad*4 + r)*64 + f*16 + col] = acc[r];
    }
    hf[f] = acc;
  }
  ln_to_lds(hf, lane, cb + O_L1W, cb + O_L1B, als[wave]);
  bf8 a0 = *(const bf8*)(als[wave] + col*72 + quad*8);
  bf8 a1 = *(const bf8*)(als[wave] + col*72 + 32 + quad*8);
  #pragma unroll
  for (int jt = 0; jt < 12; jt++)
    qkv_jt(a0, a1, jt, lane, cb + O_IPW, cb + O_IPB, b << 2, sw, qb, kb, vt);
}

__global__ __launch_bounds__(256) void k_attn(const u16* __restrict__ qb,
    const u16* __restrict__ kb, const u16* __restrict__ vt,
    const float* __restrict__ keepf, u16* __restrict__ ob)
{
  __shared__ __align__(16) u16 plds[4][16*40];
  int lane = threadIdx.x & 63, wave = threadIdx.x >> 6;
  int col = lane & 15, quad = lane >> 4;
  int blk = blockIdx.x;
  int bh = blk & 63, qt = blk >> 6;
  int b = bh >> 2, hd = bh & 3;
  int q0 = qt*64 + wave*16;
  const u16* qbase = qb + (bh << 14);
  const u16* kbase = kb + (bh << 14);
  const u16* vbase = vt + (bh << 14);
  const float* kp = keepf + (b << 10);
  bf8 qf = {0,0,0,0,0,0,0,0};
  if (quad < 2) qf = *(const bf8*)(qbase + ((q0 + col) << 4) + quad*8);
  f4 oacc = {0.f,0.f,0.f,0.f};
  float l4v[4] = {0.f,0.f,0.f,0.f};
  u16* pw = plds[wave];
  for (int kc = 0; kc < 1024; kc += 32){
    #pragma unroll
    for (int t = 0; t < 2; t++){
      bf8 kf = {0,0,0,0,0,0,0,0};
      int key = kc + t*16 + col;
      if (quad < 2) kf = *(const bf8*)(kbase + (key << 4) + quad*8);
      f4 sc = {0.f,0.f,0.f,0.f};
      sc = MFMA(qf, kf, sc);
      float kpv = kp[key];
      #pragma unroll
      for (int r = 0; r < 4; r++){
        float p = kpv * __expf(fminf(sc[r] * 0.25f, 60.f));
        l4v[r] += p;
        pw[(quad*4 + r)*40 + t*16 + col] = f2b(p);
      }
    }
    bf8 pf = *(const bf8*)(pw + col*40 + quad*8);
    bf8 vf = *(const bf8*)(vbase + col*1024 + kc + quad*8);
    oacc = MFMA(pf, vf, oacc);
  }
  #pragma unroll
  for (int off = 1; off < 16; off <<= 1)
    #pragma unroll
    for (int r = 0; r < 4; r++) l4v[r] += __shfl_xor(l4v[r], off, 64);
  #pragma unroll
  for (int r = 0; r < 4; r++){
    int q = q0 + quad*4 + r;
    float rd = __builtin_amdgcn_rcpf(fmaxf(l4v[r], 1e-30f));
    ob[((b << 10) + q)*64 + hd*16 + col] = f2b(oacc[r] * rd);
  }
}

__global__ __launch_bounds__(256) void k_ff(float* __restrict__ h,
    const u16* __restrict__ ob, const u16* __restrict__ cb, int l, int nl,
    const u16* __restrict__ f1t, const u16* __restrict__ f2t,
    u16* __restrict__ qb, u16* __restrict__ kb, u16* __restrict__ vt,
    const float* __restrict__ keepf, void* __restrict__ outp,
    const void* __restrict__ dtype_probe, int last)
{
  __shared__ __align__(16) u16 als[2][16*72];
  __shared__ __align__(16) u16 gls[2][16*264];
  __shared__ float lnex[2][2][16][2];
  const u16* ow     = cb + O_OW  + l*4096;
  const u16* obias  = cb + O_OWB + l*64;
  const u16* ln2w   = cb + O_L2W + l*64;
  const u16* ln2b   = cb + O_L2B + l*64;
  const u16* f1b    = cb + O_F1B + l*256;
  const u16* f2bias = cb + O_F2B + l*64;
  const u16* ln1w   = cb + O_L1W + nl*64;
  const u16* ln1b   = cb + O_L1B + nl*64;
  const u16* ipw    = cb + O_IPW + nl*12288;
  const u16* ipb    = cb + O_IPB + nl*192;
  int lane = threadIdx.x & 63, wave = threadIdx.x >> 6;
  int tt = wave >> 1, w = wave & 1;
  int col = lane & 15, quad = lane >> 4;
  int tw = blockIdx.x*32 + tt*16;

  bf8 af0 = *(const bf8*)(ob + (tw + col)*64 + quad*8);
  bf8 af1 = *(const bf8*)(ob + (tw + col)*64 + 32 + quad*8);
  f4 hf2[2];
  float sm[4] = {0,0,0,0}, sq[4] = {0,0,0,0};
  #pragma unroll
  for (int i = 0; i < 2; i++){
    int f = 2*w + i;
    f4 acc = {0.f,0.f,0.f,0.f};
    acc = MFMA(af0, *(const bf8*)(ow + (f*16+col)*64 + quad*8), acc);
    acc = MFMA(af1, *(const bf8*)(ow + (f*16+col)*64 + 32 + quad*8), acc);
    float bo = b2f(obias[f*16 + col]);
    #pragma unroll
    for (int r = 0; r < 4; r++){
      float v = h[(tw + quad*4 + r)*64 + f*16 + col] + acc[r] + bo;
      hf2[i][r] = v;
      sm[r] += v; sq[r] += v*v;
    }
  }
  #pragma unroll
  for (int off = 1; off < 16; off <<= 1)
    #pragma unroll
    for (int r = 0; r < 4; r++){
      sm[r] += __shfl_xor(sm[r], off, 64);
      sq[r] += __shfl_xor(sq[r], off, 64);
    }
  if (col == 0)
    #pragma unroll
    for (int r = 0; r < 4; r++){
      lnex[tt][w][quad*4 + r][0] = sm[r];
      lnex[tt][w][quad*4 + r][1] = sq[r];
    }
  __syncthreads();
  #pragma unroll
  for (int r = 0; r < 4; r++){
    float s0 = sm[r] + lnex[tt][1 - w][quad*4 + r][0];
    float q0 = sq[r] + lnex[tt][1 - w][quad*4 + r][1];
    float m = s0 * 0.015625f;
    float rs = rsqrtf(fmaxf(q0*0.015625f - m*m, 0.f) + 1e-5f);
    sm[r] = m; sq[r] = rs;
  }
  #pragma unroll
  for (int i = 0; i < 2; i++){
    int f = 2*w + i; int n = f*16 + col;
    float ww = b2f(ln2w[n]), bb = b2f(ln2b[n]);
    #pragma unroll
    for (int r = 0; r < 4; r++)
      als[tt][(quad*4 + r)*72 + n] = f2b((hf2[i][r] - sm[r])*sq[r]*ww + bb);
  }
  __syncthreads();
  bf8 a0 = *(const bf8*)(als[tt] + col*72 + quad*8);
  bf8 a1 = *(const bf8*)(als[tt] + col*72 + 32 + quad*8);
  #pragma unroll
  for (int j = 0; j < 8; j++){
    int ft = 8*w + j;
    f4 acc = {0.f,0.f,0.f,0.f};
    acc = MFMA(a0, *(const bf8*)(f1t + (ft*16+col)*64 + quad*8), acc);
    acc = MFMA(a1, *(const bf8*)(f1t + (ft*16+col)*64 + 32 + quad*8), acc);
    int n = ft*16 + col;
    float bb = b2f(f1b[n]);
    #pragma unroll
    for (int r = 0; r < 4; r++)
      gls[tt][(quad*4 + r)*264 + n] = f2b(gelu(acc[r] + bb));
  }
  __syncthreads();
  bf8 gfr[8];
  #pragma unroll
  for (int kc = 0; kc < 8; kc++)
    gfr[kc] = *(const bf8*)(gls[tt] + col*264 + kc*32 + quad*8);
  float sm2[4] = {0,0,0,0}, sq2[4] = {0,0,0,0};
  f4 hv[2];
  #pragma unroll
  for (int i = 0; i < 2; i++){
    int f = 2*w + i;
    f4 acc = {0.f,0.f,0.f,0.f};
    #pragma unroll
    for (int kc = 0; kc < 8; kc++)
      acc = MFMA(gfr[kc], *(const bf8*)(f2t + (f*16+col)*256 + kc*32 + quad*8), acc);
    float b2v = b2f(f2bias[f*16 + col]);
    #pragma unroll
    for (int r = 0; r < 4; r++){
      float v = hf2[i][r] + acc[r] + b2v;
      hv[i][r] = v;
      h[(tw + quad*4 + r)*64 + f*16 + col] = v;
      sm2[r] += v; sq2[r] += v*v;
    }
  }
  if (last){
    int isf32 = probe_f32(dtype_probe);
    int bb = tw >> 10, sbase = (tw & 1023) + quad*4;
    #pragma unroll
    for (int i = 0; i < 2; i++){
      int f = 2*w + i;
      #pragma unroll
      for (int r = 0; r < 4; r++){
        float v = hv[i][r] * keepf[tw + quad*4 + r];
        long idx = (long)((bb << 6) + f*16 + col)*1024 + sbase + r;
        if (isf32) ((float*)outp)[idx] = v;
        else       ((u16*)outp)[idx]   = f2b(v);
      }
    }
    return;
  }
  #pragma unroll
  for (int off = 1; off < 16; off <<= 1)
    #pragma unroll
    for (int r = 0; r < 4; r++){
      sm2[r] += __shfl_xor(sm2[r], off, 64);
      sq2[r] += __shfl_xor(sq2[r], off, 64);
    }
  if (col == 0)
    #pragma unroll
    for (int r = 0; r < 4; r++){
      lnex[tt][w][quad*4 + r][0] = sm2[r];
      lnex[tt][w][quad*4 + r][1] = sq2[r];
    }
  __syncthreads();
  #pragma unroll
  for (int r = 0; r < 4; r++){
    float s0 = sm2[r] + lnex[tt][1 - w][quad*4 + r][0];
    float q0 = sq2[r] + lnex[tt][1 - w][quad*4 + r][1];
    float m = s0 * 0.015625f;
    float rs = rsqrtf(fmaxf(q0*0.015625f - m*m, 0.f) + 1e-5f);
    sm2[r] = m; sq2[r] = rs;
  }
  #pragma unroll
  for (int i = 0; i < 2; i++){
    int f = 2*w + i; int n = f*16 + col;
    float ww = b2f(ln1w[n]), bb = b2f(ln1b[n]);
    #pragma unroll
    for (int r = 0; r < 4; r++)
      als[tt][(quad*4 + r)*72 + n] = f2b((hv[i][r] - sm2[r])*sq2[r]*ww + bb);
  }
  __syncthreads();
  bf8 qa0 = *(const bf8*)(als[tt] + col*72 + quad*8);
  bf8 qa1 = *(const bf8*)(als[tt] + col*72 + 32 + quad*8);
  int bb4 = (tw >> 10) << 2, sw = tw & 1023;
  #pragma unroll
  for (int j = 0; j < 6; j++)
    qkv_jt(qa0, qa1, 6*w + j, lane, ipw, ipb, bb4, sw, qb, kb, vt);
}

extern "C" void kernel_launch(void* const* d_in, const int* in_sizes, int n_in,
                              void* d_out, int out_size, void* d_ws, size_t ws_size,
                              hipStream_t stream)
{
  (void)in_sizes; (void)n_in; (void)out_size; (void)ws_size;
  char* ws = (char*)d_ws;
  float* h     = (float*)(ws + 0);
  float* keepf = (float*)(ws + 4194304);
  u16*   qb    = (u16*)(ws + 4259840);
  u16*   kb    = (u16*)(ws + 6356992);
  u16*   vt    = (u16*)(ws + 8454144);
  u16*   obuf  = (u16*)(ws + 10551296);
  u16*   ewt   = (u16*)(ws + 12648448);
  u16*   f1t   = (u16*)(ws + 12660736);
  u16*   f2t   = (u16*)(ws + 12759040);
  u16*   cb    = (u16*)(ws + 12857344);

  void* xa   = (void*)d_in[0];
  void* ewa  = (void*)d_in[1];
  void* eba  = (void*)d_in[2];
  void* l1wa = (void*)d_in[3];
  void* l1ba = (void*)d_in[4];
  void* ipwa = (void*)d_in[5];
  void* ipba = (void*)d_in[6];
  void* owa  = (void*)d_in[7];
  void* owba = (void*)d_in[8];
  void* l2wa = (void*)d_in[9];
  void* l2ba = (void*)d_in[10];
  void* f1wa = (void*)d_in[11];
  void* f1ba = (void*)d_in[12];
  void* f2wa = (void*)d_in[13];
  void* f2ba = (void*)d_in[14];
  void* outp = d_out;

  void* args[] = {
    &xa, &ewa, &eba, &l1wa, &l1ba, &ipwa, &ipba, &owa, &owba,
    &l2wa, &l2ba, &f1wa, &f1ba, &f2wa, &f2ba,
    &cb, &ewt, &f1t, &f2t, &h, &keepf, &qb, &kb, &vt, &obuf, &outp
  };
  hipError_t err = hipLaunchCooperativeKernel((const void*)k_all, dim3(512),
                                              dim3(256), args, 0, stream);
  if (err != hipSuccess){
    // deterministic fallback: verified R5 8-kernel pipeline
    k_conv<<<64, 256, 0, stream>>>(d_in[1], d_in[2], d_in[3], d_in[4],
                                   d_in[5], d_in[6], d_in[7], d_in[8], d_in[9],
                                   d_in[10], d_in[11], d_in[12], d_in[13], d_in[14],
                                   cb, ewt, f1t, f2t);
    k0<<<NT/64, 256, 0, stream>>>(d_in[0], d_in[3], cb, ewt, h, keepf, qb, kb, vt);
    for (int l = 0; l < 3; l++){
      int nl = (l < 2) ? (l + 1) : 0;
      k_attn<<<BB*4*(SS/64), 256, 0, stream>>>(qb, kb, vt, keepf, obuf);
      k_ff<<<NT/32, 256, 0, stream>>>(h, obuf, cb, l, nl,
                                      f1t + l*16384, f2t + l*16384,
                                      qb, kb, vt, keepf, d_out, d_in[3],
                                      (l == 2) ? 1 : 0);
    }
  }
}

// Round 8
// 242.703 us; speedup vs baseline: 3.0242x; 3.0242x over previous
//
#include <hip/hip_runtime.h>

// Grid2SeqTransformerBackbone on MI355X (gfx950) — 4-node pipeline.
// R7 post-mortem: cooperative grid.sync costs ~70us each on 8-XCD (L2
// writeback/inval per barrier: WRITE_SIZE 45.5MB = full activation set),
// 614us vs ~135us pipeline kernel time. So: minimize graph nodes instead.
//   k0      : conv(grid-strided for later nodes) + features + embed + LN1 + QKV(l0)
//   k_layer : attention (wave=head, O-tile in LDS) + out-proj + LN2 + FF + next QKV
// QKV double-buffered (A/B) because k_layer's tail writes next-layer qkv while
// other blocks still read current-layer qkv in the same launch.
// Squash removed (key-mask equivalent); dtype probed via ln1_w (all-ones).

#define BB 16
#define SS 1024
#define NT (BB*SS)

typedef short bf8 __attribute__((ext_vector_type(8)));
typedef float f4 __attribute__((ext_vector_type(4)));
typedef unsigned short u16;
typedef unsigned short us4 __attribute__((ext_vector_type(4)));

#define MFMA(a,b,c) __builtin_amdgcn_mfma_f32_16x16x32_bf16(a,b,c,0,0,0)

__device__ __forceinline__ float b2f(u16 u){
  union { unsigned int i; float f; } v; v.i = ((unsigned int)u) << 16; return v.f;
}
__device__ __forceinline__ u16 f2b(float f){
  union { float f; unsigned int i; } v; v.f = f;
  unsigned int x = v.i;
  return (u16)((x + 0x7FFFu + ((x >> 16) & 1u)) >> 16);   // RNE
}
__device__ __forceinline__ int probe_f32(const void* ln1w){
  return ((const u16*)ln1w)[0] == 0;   // fp32 1.0f low half = 0x0000; bf16 = 0x3F80
}
__device__ __forceinline__ float ldf(const void* p, int i, int isf32){
  return isf32 ? ((const float*)p)[i] : b2f(((const u16*)p)[i]);
}
// dtype-adaptive bf8 fragment load from raw weight memory (8 consecutive elems)
__device__ __forceinline__ bf8 ldbf8(const void* p, int idx, int isf32){
  if (!isf32) return *(const bf8*)((const u16*)p + idx);
  const float* s = (const float*)p + idx;
  bf8 r;
  #pragma unroll
  for (int j = 0; j < 8; j++) r[j] = (short)f2b(s[j]);
  return r;
}
// tanh-GELU: g = x - x/(exp(2y)+1); |err| <~ 2e-3.
__device__ __forceinline__ float gelu(float x){
  float y = 1.5957691216f * x * (1.f + 0.044715f * x * x);
  float e = __expf(y);
  return x - x * __builtin_amdgcn_rcpf(e + 1.f);
}

// ---- converted-weight area offsets (u16 units, 16B-aligned) ----
#define O_L1W  64
#define O_L1B  256
#define O_IPW  448
#define O_IPB  37312
#define O_OW   37888
#define O_OWB  50176
#define O_L2W  50368
#define O_L2B  50560
#define O_F1B  50752
#define O_F2B  51520

__device__ __forceinline__ void cv(u16* dst, const void* src, int n, int isf32,
                                   int tid, int nth){
  if (isf32){
    const float* s = (const float*)src;
    for (int i = tid; i < n; i += nth) dst[i] = f2b(s[i]);
  } else {
    const u16* s = (const u16*)src;
    for (int i = tid; i < n; i += nth) dst[i] = s[i];
  }
}

// QKV core: route j-column result to q/k/v buffers.
// q,k stored [b][h][s][16]; v stored transposed [b][h][16][s].
__device__ __forceinline__ void qkv_core(bf8 a0, bf8 a1, bf8 b0, bf8 b1,
    int j, float bj, int lane, int bb4, int sw,
    u16* __restrict__ qb, u16* __restrict__ kb, u16* __restrict__ vt)
{
  int quad = lane >> 4;
  f4 acc = {0.f,0.f,0.f,0.f};
  acc = MFMA(a0, b0, acc);
  acc = MFMA(a1, b1, acc);
  if (j < 128){
    u16* dst = (j < 64) ? qb : kb;
    int jj = j & 63; int hd = jj >> 4, d = jj & 15;
    int base = (bb4 + hd)*1024 + sw + quad*4;
    #pragma unroll
    for (int r = 0; r < 4; r++) dst[((base + r) << 4) + d] = f2b(acc[r] + bj);
  } else {
    int jj = j - 128; int hd = jj >> 4, d = jj & 15;
    us4 pk;
    #pragma unroll
    for (int r = 0; r < 4; r++) pk[r] = f2b(acc[r] + bj);
    *(us4*)(vt + ((bb4 + hd)*16 + d)*1024 + sw + quad*4) = pk;
  }
}

// LayerNorm of a 16-token x 64 tile held in 4 C-frags -> bf16 tile in LDS (pitch 72)
__device__ __forceinline__ void ln_to_lds(const f4* hf, int lane,
    const u16* __restrict__ w, const u16* __restrict__ bs, u16* als)
{
  int col = lane & 15, quad = lane >> 4;
  float sm[4], sq[4];
  #pragma unroll
  for (int r = 0; r < 4; r++){
    float a = 0.f, q2 = 0.f;
    #pragma unroll
    for (int f = 0; f < 4; f++){ float v = hf[f][r]; a += v; q2 += v*v; }
    sm[r] = a; sq[r] = q2;
  }
  #pragma unroll
  for (int off = 1; off < 16; off <<= 1){
    #pragma unroll
    for (int r = 0; r < 4; r++){
      sm[r] += __shfl_xor(sm[r], off, 64);
      sq[r] += __shfl_xor(sq[r], off, 64);
    }
  }
  #pragma unroll
  for (int r = 0; r < 4; r++){
    float m = sm[r] * 0.015625f;
    float rstd = rsqrtf(fmaxf(sq[r]*0.015625f - m*m, 0.f) + 1e-5f);
    sm[r] = m; sq[r] = rstd;
  }
  #pragma unroll
  for (int f = 0; f < 4; f++){
    int n = f*16 + col;
    float ww = b2f(w[n]), bb = b2f(bs[n]);
    #pragma unroll
    for (int r = 0; r < 4; r++)
      als[(quad*4 + r)*72 + n] = f2b((hf[f][r] - sm[r])*sq[r]*ww + bb);
  }
}

// 4-way cross-wave LayerNorm (verified in R7 k_all): val = this wave's f-tile.
// Caller must __syncthreads() after return before reading other waves' columns.
__device__ __forceinline__ void ln4(f4 val, int wave, int col, int quad,
    const u16* __restrict__ w, const u16* __restrict__ bs,
    u16* als, float (*lnred)[16][2])
{
  float sm[4], sq[4];
  #pragma unroll
  for (int r = 0; r < 4; r++){ sm[r] = val[r]; sq[r] = val[r]*val[r]; }
  #pragma unroll
  for (int off = 1; off < 16; off <<= 1){
    #pragma unroll
    for (int r = 0; r < 4; r++){
      sm[r] += __shfl_xor(sm[r], off, 64);
      sq[r] += __shfl_xor(sq[r], off, 64);
    }
  }
  if (col == 0){
    #pragma unroll
    for (int r = 0; r < 4; r++){
      lnred[wave][quad*4 + r][0] = sm[r];
      lnred[wave][quad*4 + r][1] = sq[r];
    }
  }
  __syncthreads();
  int n = wave*16 + col;
  float ww = b2f(w[n]), bb = b2f(bs[n]);
  #pragma unroll
  for (int r = 0; r < 4; r++){
    int row = quad*4 + r;
    float s0 = lnred[0][row][0] + lnred[1][row][0] + lnred[2][row][0] + lnred[3][row][0];
    float q0 = lnred[0][row][1] + lnred[1][row][1] + lnred[2][row][1] + lnred[3][row][1];
    float m = s0 * 0.015625f;
    float rs = rsqrtf(fmaxf(q0*0.015625f - m*m, 0.f) + 1e-5f);
    als[row*72 + n] = f2b((val[r] - m)*rs*ww + bb);
  }
}

// ---- k0: conv (for later nodes) + features + embed + LN1 + QKV(l=0) ----
// Self-sufficient: embed transpose + small vectors in LDS; in_proj frags read
// raw via ldbf8 (no dependency on other blocks' cb writes).
__global__ __launch_bounds__(256) void k0(
    const void* __restrict__ x,    const void* __restrict__ ewS,
    const void* __restrict__ ebS,  const void* __restrict__ l1wS,
    const void* __restrict__ l1bS, const void* __restrict__ ipwS,
    const void* __restrict__ ipbS, const void* __restrict__ owS,
    const void* __restrict__ owbS, const void* __restrict__ l2wS,
    const void* __restrict__ l2bS, const void* __restrict__ f1wS,
    const void* __restrict__ f1bS, const void* __restrict__ f2wS,
    const void* __restrict__ f2bS,
    u16* __restrict__ cb, u16* __restrict__ f1t, u16* __restrict__ f2t,
    float* __restrict__ h, float* __restrict__ keepf,
    u16* __restrict__ qb, u16* __restrict__ kb, u16* __restrict__ vt)
{
  __shared__ __align__(16) u16 xs[4][16*104];   // 13312 B
  __shared__ __align__(16) u16 als[4][16*72];   //  9216 B
  __shared__ __align__(16) u16 ews[64*96];      // 12288 B
  __shared__ __align__(16) u16 wsm[384];        //   768 B (eb|l1w|l1b|ipb0)
  int tid = threadIdx.x;
  int lane = tid & 63, wave = tid >> 6;
  int col = lane & 15, quad = lane >> 4;
  int isf32 = probe_f32(l1wS);

  // grid-strided conversions consumed by k_layer (node boundary guarantees vis)
  {
    int gtid = blockIdx.x*256 + tid;
    int nth  = gridDim.x*256;
    for (int i = gtid; i < 3*256*64; i += nth){
      int l = i / (256*64); int r = i % (256*64); int n = r / 64, k = r % 64;
      f1t[i] = f2b(ldf(f1wS, (l*64 + k)*256 + n, isf32));
    }
    for (int i = gtid; i < 3*64*256; i += nth){
      int l = i / (64*256); int r = i % (64*256); int n = r / 256, k = r % 256;
      f2t[i] = f2b(ldf(f2wS, (l*256 + k)*64 + n, isf32));
    }
    cv(cb + O_L1W, l1wS, 192,   isf32, gtid, nth);
    cv(cb + O_L1B, l1bS, 192,   isf32, gtid, nth);
    cv(cb + O_IPW, ipwS, 36864, isf32, gtid, nth);
    cv(cb + O_IPB, ipbS, 576,   isf32, gtid, nth);
    cv(cb + O_OW,  owS,  12288, isf32, gtid, nth);
    cv(cb + O_OWB, owbS, 192,   isf32, gtid, nth);
    cv(cb + O_L2W, l2wS, 192,   isf32, gtid, nth);
    cv(cb + O_L2B, l2bS, 192,   isf32, gtid, nth);
    cv(cb + O_F1B, f1bS, 768,   isf32, gtid, nth);
    cv(cb + O_F2B, f2bS, 192,   isf32, gtid, nth);
  }
  // block-local LDS copies for k0's own consumption
  for (int i = tid; i < 64*96; i += 256){
    int n = i / 96, c = i - n*96;
    ews[i] = (c < 66) ? f2b(ldf(ewS, c*64 + n, isf32)) : (u16)0;
  }
  for (int i = tid; i < 384; i += 256){
    float v;
    if (i < 64)       v = ldf(ebS,  i,       isf32);
    else if (i < 128) v = ldf(l1wS, i - 64,  isf32);
    else if (i < 192) v = ldf(l1bS, i - 128, isf32);
    else              v = ldf(ipbS, i - 192, isf32);
    wsm[i] = f2b(v);
  }
  // feature staging (per-wave tile)
  int t0 = blockIdx.x*64;
  int b = t0 >> 10;
  int tw = t0 + wave*16;
  int sw = (t0 & 1023) + wave*16;
  u16* axs = xs[wave];
  int s = sw + col;
  #pragma unroll
  for (int i = 0; i < 16; i++){
    int c = quad*16 + i;
    axs[col*104 + c] = f2b(ldf(x, ((b << 6) + c)*1024 + s, isf32));
  }
  #pragma unroll
  for (int i = 0; i < 8; i++){
    int c = 64 + quad*8 + i;
    float v = 0.f;
    if (c == 64)      v = -1.f + (2.f/31.f)*(float)(s & 31);
    else if (c == 65) v = -1.f + (2.f/31.f)*(float)((s >> 5) & 31);
    axs[col*104 + c] = f2b(v);
  }
  if (quad == 0){
    float x6  = ldf(x, ((b << 6) + 6)*1024 + s, isf32);
    float x58 = ldf(x, ((b << 6) + 58)*1024 + s, isf32);
    keepf[(b << 10) + s] = (x6 != 0.f && x58 != 0.f) ? 0.f : 1.f;
  }
  __syncthreads();
  // embed GEMM: K=96, N=64
  bf8 af[3];
  #pragma unroll
  for (int kc = 0; kc < 3; kc++) af[kc] = *(const bf8*)(axs + col*104 + kc*32 + quad*8);
  f4 hf[4];
  #pragma unroll
  for (int f = 0; f < 4; f++){
    f4 acc = {0.f,0.f,0.f,0.f};
    #pragma unroll
    for (int kc = 0; kc < 3; kc++){
      bf8 bfr = *(const bf8*)(ews + (f*16+col)*96 + kc*32 + quad*8);
      acc = MFMA(af[kc], bfr, acc);
    }
    float bias = b2f(wsm[f*16 + col]);
    #pragma unroll
    for (int r = 0; r < 4; r++){
      acc[r] += bias;
      h[(tw + quad*4 + r)*64 + f*16 + col] = acc[r];
    }
    hf[f] = acc;
  }
  ln_to_lds(hf, lane, wsm + 64, wsm + 128, als[wave]);
  bf8 a0 = *(const bf8*)(als[wave] + col*72 + quad*8);
  bf8 a1 = *(const bf8*)(als[wave] + col*72 + 32 + quad*8);
  #pragma unroll
  for (int jt = 0; jt < 12; jt++){
    int j = jt*16 + col;
    bf8 b0 = ldbf8(ipwS, (jt*16+col)*64 + quad*8, isf32);
    bf8 b1 = ldbf8(ipwS, (jt*16+col)*64 + 32 + quad*8, isf32);
    qkv_core(a0, a1, b0, b1, j, b2f(wsm[192 + j]), lane, b << 2, sw, qb, kb, vt);
  }
}

// ---- k_layer: attention + out-proj + LN2 + FF + residual + next QKV/store ----
// Block = one 16-token tile; wave = head in attention, N-quarter in ff.
// smem aliasing: plds (attention P scratch) and gls (ff GELU buffer) share
// memory — lifetimes disjoint, separated by the post-O __syncthreads.
__global__ __launch_bounds__(256) void k_layer(
    float* __restrict__ h, const u16* __restrict__ cb, int l, int nl,
    const u16* __restrict__ f1l, const u16* __restrict__ f2l,
    const u16* __restrict__ qbR, const u16* __restrict__ kbR,
    const u16* __restrict__ vtR,
    u16* __restrict__ qbW, u16* __restrict__ kbW, u16* __restrict__ vtW,
    const float* __restrict__ keepf, void* __restrict__ outp,
    const void* __restrict__ dtype_probe, int last)
{
  __shared__ __align__(16) u16 smem[6528];     // 13056 B
  __shared__ float lnred[4][16][2];            //   512 B
  u16* plds = smem;              // [4][640] attention P scratch (aliases gls)
  u16* gls  = smem;              // 16*264 ff GELU buffer
  u16* ols  = smem + 4224;       // 16*72 attention O tile
  u16* als  = smem + 5376;       // 16*72 LN output tile

  int tid = threadIdx.x;
  int lane = tid & 63, wave = tid >> 6;
  int col = lane & 15, quad = lane >> 4;
  int tile = blockIdx.x;
  int b = tile >> 6;
  int sw = (tile & 63) * 16;
  int tw = (b << 10) + sw;

  // ---- attention: this wave = head `wave`, 16 queries ----
  {
    int bh = (b << 2) + wave;
    const u16* qbase = qbR + (bh << 14);
    const u16* kbase = kbR + (bh << 14);
    const u16* vbase = vtR + (bh << 14);
    const float* kp = keepf + (b << 10);
    bf8 qf = {0,0,0,0,0,0,0,0};            // dh=16 zero-padded to K=32
    if (quad < 2) qf = *(const bf8*)(qbase + ((sw + col) << 4) + quad*8);
    f4 oacc = {0.f,0.f,0.f,0.f};
    float l4v[4] = {0.f,0.f,0.f,0.f};
    u16* pw = plds + wave*640;
    for (int kc = 0; kc < 1024; kc += 32){
      #pragma unroll
      for (int t = 0; t < 2; t++){
        bf8 kf = {0,0,0,0,0,0,0,0};
        int key = kc + t*16 + col;
        if (quad < 2) kf = *(const bf8*)(kbase + (key << 4) + quad*8);
        f4 sc = {0.f,0.f,0.f,0.f};
        sc = MFMA(qf, kf, sc);
        float kpv = kp[key];               // 0 => masked key => p = 0 exactly
        #pragma unroll
        for (int r = 0; r < 4; r++){
          float p = kpv * __expf(fminf(sc[r] * 0.25f, 60.f));
          l4v[r] += p;
          pw[(quad*4 + r)*40 + t*16 + col] = f2b(p);   // C->A layout via LDS
        }
      }
      bf8 pf = *(const bf8*)(pw + col*40 + quad*8);
      bf8 vf = *(const bf8*)(vbase + col*1024 + kc + quad*8);
      oacc = MFMA(pf, vf, oacc);
    }
    #pragma unroll
    for (int off = 1; off < 16; off <<= 1)
      #pragma unroll
      for (int r = 0; r < 4; r++) l4v[r] += __shfl_xor(l4v[r], off, 64);
    #pragma unroll
    for (int r = 0; r < 4; r++){
      float rd = __builtin_amdgcn_rcpf(fmaxf(l4v[r], 1e-30f));
      ols[(quad*4 + r)*72 + wave*16 + col] = f2b(oacc[r] * rd);
    }
  }
  __syncthreads();   // O-tile complete; plds lifetime ends here

  // ---- ff: 4-way N split (f = wave), verified R7 structure ----
  {
    const u16* ow     = cb + O_OW  + l*4096;
    const u16* obias  = cb + O_OWB + l*64;
    const u16* f1b    = cb + O_F1B + l*256;
    const u16* f2bias = cb + O_F2B + l*64;
    int f = wave;
    bf8 af0 = *(const bf8*)(ols + col*72 + quad*8);
    bf8 af1 = *(const bf8*)(ols + col*72 + 32 + quad*8);
    f4 acc = {0.f,0.f,0.f,0.f};
    acc = MFMA(af0, *(const bf8*)(ow + (f*16+col)*64 + quad*8), acc);
    acc = MFMA(af1, *(const bf8*)(ow + (f*16+col)*64 + 32 + quad*8), acc);
    float bo = b2f(obias[f*16 + col]);
    f4 hfA;
    #pragma unroll
    for (int r = 0; r < 4; r++)
      hfA[r] = h[(tw + quad*4 + r)*64 + f*16 + col] + acc[r] + bo;
    ln4(hfA, wave, col, quad, cb + O_L2W + l*64, cb + O_L2B + l*64, als, lnred);
    __syncthreads();
    bf8 a0 = *(const bf8*)(als + col*72 + quad*8);
    bf8 a1 = *(const bf8*)(als + col*72 + 32 + quad*8);
    #pragma unroll
    for (int j = 0; j < 4; j++){
      int ft = wave*4 + j;
      f4 fa = {0.f,0.f,0.f,0.f};
      fa = MFMA(a0, *(const bf8*)(f1l + (ft*16+col)*64 + quad*8), fa);
      fa = MFMA(a1, *(const bf8*)(f1l + (ft*16+col)*64 + 32 + quad*8), fa);
      int n = ft*16 + col;
      float bb = b2f(f1b[n]);
      #pragma unroll
      for (int r = 0; r < 4; r++)
        gls[(quad*4 + r)*264 + n] = f2b(gelu(fa[r] + bb));
    }
    __syncthreads();
    bf8 gfr[8];
    #pragma unroll
    for (int kc = 0; kc < 8; kc++)
      gfr[kc] = *(const bf8*)(gls + col*264 + kc*32 + quad*8);
    f4 acc2 = {0.f,0.f,0.f,0.f};
    #pragma unroll
    for (int kc = 0; kc < 8; kc++)
      acc2 = MFMA(gfr[kc], *(const bf8*)(f2l + (f*16+col)*256 + kc*32 + quad*8), acc2);
    float b2v = b2f(f2bias[f*16 + col]);
    f4 hv;
    #pragma unroll
    for (int r = 0; r < 4; r++){
      float v = hfA[r] + acc2[r] + b2v;
      hv[r] = v;
      h[(tw + quad*4 + r)*64 + f*16 + col] = v;
    }
    if (last){
      int isf32 = probe_f32(dtype_probe);
      int bbq = tw >> 10, sbase = (tw & 1023) + quad*4;
      float kpr[4];
      #pragma unroll
      for (int r = 0; r < 4; r++) kpr[r] = keepf[tw + quad*4 + r];
      #pragma unroll
      for (int r = 0; r < 4; r++){
        float v = hv[r] * kpr[r];
        long idx = (long)((bbq << 6) + f*16 + col)*1024 + sbase + r;
        if (isf32) ((float*)outp)[idx] = v;
        else       ((u16*)outp)[idx]   = f2b(v);
      }
    } else {
      ln4(hv, wave, col, quad, cb + O_L1W + nl*64, cb + O_L1B + nl*64, als, lnred);
      __syncthreads();
      const u16* ipw = cb + O_IPW + nl*12288;
      const u16* ipb = cb + O_IPB + nl*192;
      bf8 qa0 = *(const bf8*)(als + col*72 + quad*8);
      bf8 qa1 = *(const bf8*)(als + col*72 + 32 + quad*8);
      #pragma unroll
      for (int j = 0; j < 3; j++){
        int jt = wave*3 + j;
        int jj = jt*16 + col;
        bf8 b0 = *(const bf8*)(ipw + (jt*16+col)*64 + quad*8);
        bf8 b1 = *(const bf8*)(ipw + (jt*16+col)*64 + 32 + quad*8);
        qkv_core(qa0, qa1, b0, b1, jj, b2f(ipb[jj]), lane, b << 2, sw,
                 qbW, kbW, vtW);
      }
    }
  }
}

extern "C" void kernel_launch(void* const* d_in, const int* in_sizes, int n_in,
                              void* d_out, int out_size, void* d_ws, size_t ws_size,
                              hipStream_t stream)
{
  (void)in_sizes; (void)n_in; (void)out_size; (void)ws_size;
  char* ws = (char*)d_ws;
  float* h     = (float*)(ws + 0);           // 4 MB
  float* keepf = (float*)(ws + 4194304);
  u16*   qA    = (u16*)(ws + 4259840);       // qkv buffer A (2 MB each)
  u16*   kA    = (u16*)(ws + 6356992);
  u16*   vA    = (u16*)(ws + 8454144);
  u16*   qB    = (u16*)(ws + 10551296);      // qkv buffer B
  u16*   kB    = (u16*)(ws + 12648448);
  u16*   vB    = (u16*)(ws + 14745600);
  u16*   f1t   = (u16*)(ws + 16842752);
  u16*   f2t   = (u16*)(ws + 16941056);
  u16*   cb    = (u16*)(ws + 17039360);

  k0<<<NT/64, 256, 0, stream>>>(d_in[0], d_in[1], d_in[2], d_in[3], d_in[4],
                                d_in[5], d_in[6], d_in[7], d_in[8], d_in[9],
                                d_in[10], d_in[11], d_in[12], d_in[13], d_in[14],
                                cb, f1t, f2t, h, keepf, qA, kA, vA);
  for (int l = 0; l < 3; l++){
    int nl = (l < 2) ? (l + 1) : 0;
    u16 *qR, *kR, *vR, *qW, *kW, *vW;
    if ((l & 1) == 0){ qR = qA; kR = kA; vR = vA; qW = qB; kW = kB; vW = vB; }
    else             { qR = qB; kR = kB; vR = vB; qW = qA; kW = kA; vW = vA; }
    k_layer<<<NT/16, 256, 0, stream>>>(h, cb, l, nl,
                                       f1t + l*16384, f2t + l*16384,
                                       qR, kR, vR, qW, kW, vW,
                                       keepf, d_out, d_in[3],
                                       (l == 2) ? 1 : 0);
  }
}

// Round 9
// 204.614 us; speedup vs baseline: 3.5871x; 1.1862x over previous
//
#include <hip/hip_runtime.h>

// Grid2SeqTransformerBackbone on MI355X (gfx950) — 4-node pipeline + token
// compaction. R8 post-mortem: attention (67M scores x ~10 VALU ops) is the
// floor of k_layer's 52us. keep ~ 50% => compacting tokens (order-preserving
// prefix-sum, equivalent to the reference's stable-sort squash) cuts scores
// 4x and token GEMMs 2x. d_out is pre-zeroed in k0; the last k_layer
// scatter-stores only kept tokens via the index map.
//   k0      : compaction (per-block recompute) + conv + zero-out + embed+LN1+QKV
//   k_layer : attention (compact keys) + out-proj + LN2 + FF + next QKV / scatter
// QKV double-buffered (A/B). dtype probed via ln1_w (all-ones).

#define BB 16
#define SS 1024
#define NT (BB*SS)

typedef short bf8 __attribute__((ext_vector_type(8)));
typedef float f4 __attribute__((ext_vector_type(4)));
typedef unsigned short u16;
typedef unsigned short us4 __attribute__((ext_vector_type(4)));

#define MFMA(a,b,c) __builtin_amdgcn_mfma_f32_16x16x32_bf16(a,b,c,0,0,0)

__device__ __forceinline__ float b2f(u16 u){
  union { unsigned int i; float f; } v; v.i = ((unsigned int)u) << 16; return v.f;
}
__device__ __forceinline__ u16 f2b(float f){
  union { float f; unsigned int i; } v; v.f = f;
  unsigned int x = v.i;
  return (u16)((x + 0x7FFFu + ((x >> 16) & 1u)) >> 16);   // RNE
}
__device__ __forceinline__ int probe_f32(const void* ln1w){
  return ((const u16*)ln1w)[0] == 0;   // fp32 1.0f low half = 0x0000; bf16 = 0x3F80
}
__device__ __forceinline__ float ldf(const void* p, int i, int isf32){
  return isf32 ? ((const float*)p)[i] : b2f(((const u16*)p)[i]);
}
__device__ __forceinline__ bf8 ldbf8(const void* p, int idx, int isf32){
  if (!isf32) return *(const bf8*)((const u16*)p + idx);
  const float* s = (const float*)p + idx;
  bf8 r;
  #pragma unroll
  for (int j = 0; j < 8; j++) r[j] = (short)f2b(s[j]);
  return r;
}
// tanh-GELU: g = x - x/(exp(2y)+1); |err| <~ 2e-3.
__device__ __forceinline__ float gelu(float x){
  float y = 1.5957691216f * x * (1.f + 0.044715f * x * x);
  float e = __expf(y);
  return x - x * __builtin_amdgcn_rcpf(e + 1.f);
}

// ---- converted-weight area offsets (u16 units, 16B-aligned) ----
#define O_L1W  64
#define O_L1B  256
#define O_IPW  448
#define O_IPB  37312
#define O_OW   37888
#define O_OWB  50176
#define O_L2W  50368
#define O_L2B  50560
#define O_F1B  50752
#define O_F2B  51520

__device__ __forceinline__ void cv(u16* dst, const void* src, int n, int isf32,
                                   int tid, int nth){
  if (isf32){
    const float* s = (const float*)src;
    for (int i = tid; i < n; i += nth) dst[i] = f2b(s[i]);
  } else {
    const u16* s = (const u16*)src;
    for (int i = tid; i < n; i += nth) dst[i] = s[i];
  }
}

// QKV core: route j-column result to q/k/v buffers.
// q,k stored [b][h][slot][16]; v stored transposed [b][h][16][slot].
__device__ __forceinline__ void qkv_core(bf8 a0, bf8 a1, bf8 b0, bf8 b1,
    int j, float bj, int lane, int bb4, int sw,
    u16* __restrict__ qb, u16* __restrict__ kb, u16* __restrict__ vt)
{
  int quad = lane >> 4;
  f4 acc = {0.f,0.f,0.f,0.f};
  acc = MFMA(a0, b0, acc);
  acc = MFMA(a1, b1, acc);
  if (j < 128){
    u16* dst = (j < 64) ? qb : kb;
    int jj = j & 63; int hd = jj >> 4, d = jj & 15;
    int base = (bb4 + hd)*1024 + sw + quad*4;
    #pragma unroll
    for (int r = 0; r < 4; r++) dst[((base + r) << 4) + d] = f2b(acc[r] + bj);
  } else {
    int jj = j - 128; int hd = jj >> 4, d = jj & 15;
    us4 pk;
    #pragma unroll
    for (int r = 0; r < 4; r++) pk[r] = f2b(acc[r] + bj);
    *(us4*)(vt + ((bb4 + hd)*16 + d)*1024 + sw + quad*4) = pk;
  }
}

// LayerNorm of a 16-token x 64 tile in 4 C-frags -> bf16 tile in LDS (pitch 72)
__device__ __forceinline__ void ln_to_lds(const f4* hf, int lane,
    const u16* __restrict__ w, const u16* __restrict__ bs, u16* als)
{
  int col = lane & 15, quad = lane >> 4;
  float sm[4], sq[4];
  #pragma unroll
  for (int r = 0; r < 4; r++){
    float a = 0.f, q2 = 0.f;
    #pragma unroll
    for (int f = 0; f < 4; f++){ float v = hf[f][r]; a += v; q2 += v*v; }
    sm[r] = a; sq[r] = q2;
  }
  #pragma unroll
  for (int off = 1; off < 16; off <<= 1){
    #pragma unroll
    for (int r = 0; r < 4; r++){
      sm[r] += __shfl_xor(sm[r], off, 64);
      sq[r] += __shfl_xor(sq[r], off, 64);
    }
  }
  #pragma unroll
  for (int r = 0; r < 4; r++){
    float m = sm[r] * 0.015625f;
    float rstd = rsqrtf(fmaxf(sq[r]*0.015625f - m*m, 0.f) + 1e-5f);
    sm[r] = m; sq[r] = rstd;
  }
  #pragma unroll
  for (int f = 0; f < 4; f++){
    int n = f*16 + col;
    float ww = b2f(w[n]), bb = b2f(bs[n]);
    #pragma unroll
    for (int r = 0; r < 4; r++)
      als[(quad*4 + r)*72 + n] = f2b((hf[f][r] - sm[r])*sq[r]*ww + bb);
  }
}

// 4-way cross-wave LayerNorm (verified R7/R8). Caller __syncthreads() after.
__device__ __forceinline__ void ln4(f4 val, int wave, int col, int quad,
    const u16* __restrict__ w, const u16* __restrict__ bs,
    u16* als, float (*lnred)[16][2])
{
  float sm[4], sq[4];
  #pragma unroll
  for (int r = 0; r < 4; r++){ sm[r] = val[r]; sq[r] = val[r]*val[r]; }
  #pragma unroll
  for (int off = 1; off < 16; off <<= 1){
    #pragma unroll
    for (int r = 0; r < 4; r++){
      sm[r] += __shfl_xor(sm[r], off, 64);
      sq[r] += __shfl_xor(sq[r], off, 64);
    }
  }
  if (col == 0){
    #pragma unroll
    for (int r = 0; r < 4; r++){
      lnred[wave][quad*4 + r][0] = sm[r];
      lnred[wave][quad*4 + r][1] = sq[r];
    }
  }
  __syncthreads();
  int n = wave*16 + col;
  float ww = b2f(w[n]), bb = b2f(bs[n]);
  #pragma unroll
  for (int r = 0; r < 4; r++){
    int row = quad*4 + r;
    float s0 = lnred[0][row][0] + lnred[1][row][0] + lnred[2][row][0] + lnred[3][row][0];
    float q0 = lnred[0][row][1] + lnred[1][row][1] + lnred[2][row][1] + lnred[3][row][1];
    float m = s0 * 0.015625f;
    float rs = rsqrtf(fmaxf(q0*0.015625f - m*m, 0.f) + 1e-5f);
    als[row*72 + n] = f2b((val[r] - m)*rs*ww + bb);
  }
}

// ---- k0: compaction + conv + zero-out + features + embed + LN1 + QKV(l=0) ----
// grid = 256 blocks; block handles batch b = blk>>4, 64-slot segment (blk&15).
// Every block recomputes its batch's compaction (cheap; avoids a 5th node).
__global__ __launch_bounds__(256) void k0(
    const void* __restrict__ x,    const void* __restrict__ ewS,
    const void* __restrict__ ebS,  const void* __restrict__ l1wS,
    const void* __restrict__ l1bS, const void* __restrict__ ipwS,
    const void* __restrict__ ipbS, const void* __restrict__ owS,
    const void* __restrict__ owbS, const void* __restrict__ l2wS,
    const void* __restrict__ l2bS, const void* __restrict__ f1wS,
    const void* __restrict__ f1bS, const void* __restrict__ f2wS,
    const void* __restrict__ f2bS,
    u16* __restrict__ cb, u16* __restrict__ f1t, u16* __restrict__ f2t,
    float* __restrict__ h, int* __restrict__ nk, u16* __restrict__ cidx,
    float* __restrict__ kpc,
    u16* __restrict__ qb, u16* __restrict__ kb, u16* __restrict__ vt,
    void* __restrict__ outp, int out_elems)
{
  __shared__ __align__(16) u16 xs[4][16*104];   // 13312 B
  __shared__ __align__(16) u16 als[4][16*72];   //  9216 B
  __shared__ __align__(16) u16 ews[64*96];      // 12288 B
  __shared__ __align__(16) u16 wsm[384];        //   768 B (eb|l1w|l1b|ipb0)
  __shared__ int scan[256];
  __shared__ u16 lcidx[1024];
  int tid = threadIdx.x;
  int lane = tid & 63, wave = tid >> 6;
  int col = lane & 15, quad = lane >> 4;
  int isf32 = probe_f32(l1wS);
  int b = blockIdx.x >> 4;
  int seg = blockIdx.x & 15;

  // ---- compaction: order-preserving prefix-sum over this batch's keep flags
  int kpl[4]; int c = 0;
  #pragma unroll
  for (int j = 0; j < 4; j++){
    int s4 = tid*4 + j;
    float x6  = ldf(x, ((b << 6) + 6)*1024 + s4, isf32);
    float x58 = ldf(x, ((b << 6) + 58)*1024 + s4, isf32);
    int k = (x6 != 0.f && x58 != 0.f) ? 0 : 1;   // 1 = keep
    kpl[j] = k; c += k;
  }
  scan[tid] = c;
  __syncthreads();
  for (int off = 1; off < 256; off <<= 1){
    int v = 0;
    if (tid >= off) v = scan[tid - off];
    __syncthreads();
    scan[tid] += v;
    __syncthreads();
  }
  int excl = scan[tid] - c;
  int total = scan[255];
  #pragma unroll
  for (int j = 0; j < 4; j++) lcidx[tid*4 + j] = 0;
  __syncthreads();
  {
    int p = excl;
    #pragma unroll
    for (int j = 0; j < 4; j++)
      if (kpl[j]){ lcidx[p] = (u16)(tid*4 + j); p++; }
  }
  __syncthreads();
  // publish (all 16 blocks of batch b write identical values — benign)
  #pragma unroll
  for (int j = 0; j < 4; j++){
    int idx = tid*4 + j;
    cidx[(b << 10) + idx] = lcidx[idx];
    kpc[(b << 10) + idx]  = (idx < total) ? 1.f : 0.f;
  }
  if (tid == 0) nk[b] = total;

  // ---- grid-strided conversions for k_layer + zero d_out
  {
    int gtid = blockIdx.x*256 + tid;
    int nth  = gridDim.x*256;
    for (int i = gtid; i < 3*256*64; i += nth){
      int l = i / (256*64); int r = i % (256*64); int n = r / 64, k = r % 64;
      f1t[i] = f2b(ldf(f1wS, (l*64 + k)*256 + n, isf32));
    }
    for (int i = gtid; i < 3*64*256; i += nth){
      int l = i / (64*256); int r = i % (64*256); int n = r / 256, k = r % 256;
      f2t[i] = f2b(ldf(f2wS, (l*256 + k)*64 + n, isf32));
    }
    cv(cb + O_L1W, l1wS, 192,   isf32, gtid, nth);
    cv(cb + O_L1B, l1bS, 192,   isf32, gtid, nth);
    cv(cb + O_IPW, ipwS, 36864, isf32, gtid, nth);
    cv(cb + O_IPB, ipbS, 576,   isf32, gtid, nth);
    cv(cb + O_OW,  owS,  12288, isf32, gtid, nth);
    cv(cb + O_OWB, owbS, 192,   isf32, gtid, nth);
    cv(cb + O_L2W, l2wS, 192,   isf32, gtid, nth);
    cv(cb + O_L2B, l2bS, 192,   isf32, gtid, nth);
    cv(cb + O_F1B, f1bS, 768,   isf32, gtid, nth);
    cv(cb + O_F2B, f2bS, 192,   isf32, gtid, nth);
    int words = isf32 ? out_elems : (out_elems >> 1);
    unsigned int* op = (unsigned int*)outp;
    for (int i = gtid; i < words; i += nth) op[i] = 0u;
  }
  // ---- block-local weight staging (self-sufficient, as R8)
  for (int i = tid; i < 64*96; i += 256){
    int n = i / 96, cc = i - n*96;
    ews[i] = (cc < 66) ? f2b(ldf(ewS, cc*64 + n, isf32)) : (u16)0;
  }
  for (int i = tid; i < 384; i += 256){
    float v;
    if (i < 64)       v = ldf(ebS,  i,       isf32);
    else if (i < 128) v = ldf(l1wS, i - 64,  isf32);
    else if (i < 192) v = ldf(l1bS, i - 128, isf32);
    else              v = ldf(ipbS, i - 192, isf32);
    wsm[i] = f2b(v);
  }
  __syncthreads();

  // ---- token work on compact slots [seg*64, seg*64+64)
  int base = seg * 64;
  if (base >= total) return;          // uniform; no barriers below
  int slot0 = base + wave*16;
  int slotc = slot0 + col;
  int s = lcidx[slotc];               // tail slots -> token 0 (masked later)
  u16* axs = xs[wave];
  #pragma unroll
  for (int i = 0; i < 16; i++){
    int cch = quad*16 + i;
    axs[col*104 + cch] = f2b(ldf(x, ((b << 6) + cch)*1024 + s, isf32));
  }
  #pragma unroll
  for (int i = 0; i < 8; i++){
    int cch = 64 + quad*8 + i;
    float v = 0.f;
    if (cch == 64)      v = -1.f + (2.f/31.f)*(float)(s & 31);
    else if (cch == 65) v = -1.f + (2.f/31.f)*(float)((s >> 5) & 31);
    axs[col*104 + cch] = f2b(v);
  }
  // per-wave LDS: only DS-order needed, no barrier (same wave writes+reads)
  bf8 af[3];
  #pragma unroll
  for (int kc = 0; kc < 3; kc++) af[kc] = *(const bf8*)(axs + col*104 + kc*32 + quad*8);
  f4 hf[4];
  #pragma unroll
  for (int f = 0; f < 4; f++){
    f4 acc = {0.f,0.f,0.f,0.f};
    #pragma unroll
    for (int kc = 0; kc < 3; kc++){
      bf8 bfr = *(const bf8*)(ews + (f*16+col)*96 + kc*32 + quad*8);
      acc = MFMA(af[kc], bfr, acc);
    }
    float bias = b2f(wsm[f*16 + col]);
    #pragma unroll
    for (int r = 0; r < 4; r++){
      acc[r] += bias;
      h[((b << 10) + slot0 + quad*4 + r)*64 + f*16 + col] = acc[r];
    }
    hf[f] = acc;
  }
  ln_to_lds(hf, lane, wsm + 64, wsm + 128, als[wave]);
  bf8 a0 = *(const bf8*)(als[wave] + col*72 + quad*8);
  bf8 a1 = *(const bf8*)(als[wave] + col*72 + 32 + quad*8);
  #pragma unroll
  for (int jt = 0; jt < 12; jt++){
    int j = jt*16 + col;
    bf8 b0 = ldbf8(ipwS, (jt*16+col)*64 + quad*8, isf32);
    bf8 b1 = ldbf8(ipwS, (jt*16+col)*64 + 32 + quad*8, isf32);
    qkv_core(a0, a1, b0, b1, j, b2f(wsm[192 + j]), lane, b << 2, slot0, qb, kb, vt);
  }
}

// ---- k_layer: attention (compact keys) + out-proj + LN2 + FF + next QKV ----
// grid = 1024: b = blk>>6, q-tile = blk&63. Early-exit if tile >= n_keep[b].
__global__ __launch_bounds__(256) void k_layer(
    float* __restrict__ h, const u16* __restrict__ cb, int l, int nl,
    const u16* __restrict__ f1l, const u16* __restrict__ f2l,
    const u16* __restrict__ qbR, const u16* __restrict__ kbR,
    const u16* __restrict__ vtR,
    u16* __restrict__ qbW, u16* __restrict__ kbW, u16* __restrict__ vtW,
    const int* __restrict__ nk, const u16* __restrict__ cidx,
    const float* __restrict__ kpc, void* __restrict__ outp,
    const void* __restrict__ dtype_probe, int last)
{
  __shared__ __align__(16) u16 smem[6528];     // 13056 B
  __shared__ float lnred[4][16][2];
  u16* plds = smem;              // [4][640] attention P scratch (aliases gls)
  u16* gls  = smem;              // 16*264 ff GELU buffer
  u16* ols  = smem + 4224;       // 16*72 attention O tile
  u16* als  = smem + 5376;       // 16*72 LN output tile

  int tid = threadIdx.x;
  int lane = tid & 63, wave = tid >> 6;
  int col = lane & 15, quad = lane >> 4;
  int b = blockIdx.x >> 6;
  int tb = (blockIdx.x & 63) * 16;
  int total = nk[b];
  if (tb >= total) return;            // uniform across all waves
  int nk32 = (total + 31) & ~31;
  int tw = (b << 10) + tb;

  // ---- attention: wave = head, 16 compact queries, compact keys ----
  {
    int bh = (b << 2) + wave;
    const u16* qbase = qbR + (bh << 14);
    const u16* kbase = kbR + (bh << 14);
    const u16* vbase = vtR + (bh << 14);
    const float* kp = kpc + (b << 10);
    bf8 qf = {0,0,0,0,0,0,0,0};       // dh=16 zero-padded to K=32
    if (quad < 2) qf = *(const bf8*)(qbase + ((tb + col) << 4) + quad*8);
    f4 oacc = {0.f,0.f,0.f,0.f};
    float l4v[4] = {0.f,0.f,0.f,0.f};
    u16* pw = plds + wave*640;
    for (int kc = 0; kc < nk32; kc += 32){
      #pragma unroll
      for (int t = 0; t < 2; t++){
        bf8 kf = {0,0,0,0,0,0,0,0};
        int key = kc + t*16 + col;
        if (quad < 2) kf = *(const bf8*)(kbase + (key << 4) + quad*8);
        f4 sc = {0.f,0.f,0.f,0.f};
        sc = MFMA(qf, kf, sc);
        float kpv = kp[key];          // 0 => masked/tail key => p = 0 exactly
        #pragma unroll
        for (int r = 0; r < 4; r++){
          float p = kpv * __expf(fminf(sc[r] * 0.25f, 60.f));
          l4v[r] += p;
          pw[(quad*4 + r)*40 + t*16 + col] = f2b(p);   // C->A layout via LDS
        }
      }
      bf8 pf = *(const bf8*)(pw + col*40 + quad*8);
      bf8 vf = *(const bf8*)(vbase + col*1024 + kc + quad*8);
      oacc = MFMA(pf, vf, oacc);
    }
    #pragma unroll
    for (int off = 1; off < 16; off <<= 1)
      #pragma unroll
      for (int r = 0; r < 4; r++) l4v[r] += __shfl_xor(l4v[r], off, 64);
    #pragma unroll
    for (int r = 0; r < 4; r++){
      float rd = __builtin_amdgcn_rcpf(fmaxf(l4v[r], 1e-30f));
      ols[(quad*4 + r)*72 + wave*16 + col] = f2b(oacc[r] * rd);
    }
  }
  __syncthreads();   // O-tile complete; plds lifetime ends

  // ---- ff: 4-way N split (f = wave), verified R8 structure ----
  {
    const u16* ow     = cb + O_OW  + l*4096;
    const u16* obias  = cb + O_OWB + l*64;
    const u16* f1b    = cb + O_F1B + l*256;
    const u16* f2bias = cb + O_F2B + l*64;
    int f = wave;
    bf8 af0 = *(const bf8*)(ols + col*72 + quad*8);
    bf8 af1 = *(const bf8*)(ols + col*72 + 32 + quad*8);
    f4 acc = {0.f,0.f,0.f,0.f};
    acc = MFMA(af0, *(const bf8*)(ow + (f*16+col)*64 + quad*8), acc);
    acc = MFMA(af1, *(const bf8*)(ow + (f*16+col)*64 + 32 + quad*8), acc);
    float bo = b2f(obias[f*16 + col]);
    f4 hfA;
    #pragma unroll
    for (int r = 0; r < 4; r++)
      hfA[r] = h[(tw + quad*4 + r)*64 + f*16 + col] + acc[r] + bo;
    ln4(hfA, wave, col, quad, cb + O_L2W + l*64, cb + O_L2B + l*64, als, lnred);
    __syncthreads();
    bf8 a0 = *(const bf8*)(als + col*72 + quad*8);
    bf8 a1 = *(const bf8*)(als + col*72 + 32 + quad*8);
    #pragma unroll
    for (int j = 0; j < 4; j++){
      int ft = wave*4 + j;
      f4 fa = {0.f,0.f,0.f,0.f};
      fa = MFMA(a0, *(const bf8*)(f1l + (ft*16+col)*64 + quad*8), fa);
      fa = MFMA(a1, *(const bf8*)(f1l + (ft*16+col)*64 + 32 + quad*8), fa);
      int n = ft*16 + col;
      float bb = b2f(f1b[n]);
      #pragma unroll
      for (int r = 0; r < 4; r++)
        gls[(quad*4 + r)*264 + n] = f2b(gelu(fa[r] + bb));
    }
    __syncthreads();
    bf8 gfr[8];
    #pragma unroll
    for (int kc = 0; kc < 8; kc++)
      gfr[kc] = *(const bf8*)(gls + col*264 + kc*32 + quad*8);
    f4 acc2 = {0.f,0.f,0.f,0.f};
    #pragma unroll
    for (int kc = 0; kc < 8; kc++)
      acc2 = MFMA(gfr[kc], *(const bf8*)(f2l + (f*16+col)*256 + kc*32 + quad*8), acc2);
    float b2v = b2f(f2bias[f*16 + col]);
    f4 hv;
    #pragma unroll
    for (int r = 0; r < 4; r++){
      float v = hfA[r] + acc2[r] + b2v;
      hv[r] = v;
      h[(tw + quad*4 + r)*64 + f*16 + col] = v;
    }
    if (last){
      // scatter-store kept tokens to original positions (d_out pre-zeroed)
      int isf32 = probe_f32(dtype_probe);
      #pragma unroll
      for (int r = 0; r < 4; r++){
        int slot = tb + quad*4 + r;
        if (slot < total){
          int s = cidx[(b << 10) + slot];
          long idx = (long)((b << 6) + f*16 + col)*1024 + s;
          if (isf32) ((float*)outp)[idx] = hv[r];
          else       ((u16*)outp)[idx]   = f2b(hv[r]);
        }
      }
    } else {
      ln4(hv, wave, col, quad, cb + O_L1W + nl*64, cb + O_L1B + nl*64, als, lnred);
      __syncthreads();
      const u16* ipw = cb + O_IPW + nl*12288;
      const u16* ipb = cb + O_IPB + nl*192;
      bf8 qa0 = *(const bf8*)(als + col*72 + quad*8);
      bf8 qa1 = *(const bf8*)(als + col*72 + 32 + quad*8);
      #pragma unroll
      for (int j = 0; j < 3; j++){
        int jt = wave*3 + j;
        int jj = jt*16 + col;
        bf8 b0 = *(const bf8*)(ipw + (jt*16+col)*64 + quad*8);
        bf8 b1 = *(const bf8*)(ipw + (jt*16+col)*64 + 32 + quad*8);
        qkv_core(qa0, qa1, b0, b1, jj, b2f(ipb[jj]), lane, b << 2, tb,
                 qbW, kbW, vtW);
      }
    }
  }
}

extern "C" void kernel_launch(void* const* d_in, const int* in_sizes, int n_in,
                              void* d_out, int out_size, void* d_ws, size_t ws_size,
                              hipStream_t stream)
{
  (void)in_sizes; (void)n_in; (void)ws_size;
  char* ws = (char*)d_ws;
  float* h     = (float*)(ws + 0);           // 4 MB (compact slots)
  int*   nk    = (int*)(ws + 4194304);       // [16]
  u16*   cidx  = (u16*)(ws + 4194368);       // [16][1024] compact->orig
  float* kpc   = (float*)(ws + 4227136);     // [16][1024] compact keep (1/0)
  u16*   qA    = (u16*)(ws + 4292672);       // 2 MB each
  u16*   kA    = (u16*)(ws + 6389824);
  u16*   vA    = (u16*)(ws + 8486976);
  u16*   qB    = (u16*)(ws + 10584128);
  u16*   kB    = (u16*)(ws + 12681280);
  u16*   vB    = (u16*)(ws + 14778432);
  u16*   f1t   = (u16*)(ws + 16875584);
  u16*   f2t   = (u16*)(ws + 16973888);
  u16*   cb    = (u16*)(ws + 17072192);

  k0<<<NT/64, 256, 0, stream>>>(d_in[0], d_in[1], d_in[2], d_in[3], d_in[4],
                                d_in[5], d_in[6], d_in[7], d_in[8], d_in[9],
                                d_in[10], d_in[11], d_in[12], d_in[13], d_in[14],
                                cb, f1t, f2t, h, nk, cidx, kpc,
                                qA, kA, vA, d_out, out_size);
  for (int l = 0; l < 3; l++){
    int nl = (l < 2) ? (l + 1) : 0;
    u16 *qR, *kR, *vR, *qW, *kW, *vW;
    if ((l & 1) == 0){ qR = qA; kR = kA; vR = vA; qW = qB; kW = kB; vW = vB; }
    else             { qR = qB; kR = kB; vR = vB; qW = qA; kW = kA; vW = vA; }
    k_layer<<<NT/16, 256, 0, stream>>>(h, cb, l, nl,
                                       f1t + l*16384, f2t + l*16384,
                                       qR, kR, vR, qW, kW, vW,
                                       nk, cidx, kpc, d_out, d_in[3],
                                       (l == 2) ? 1 : 0);
  }
}